// Round 2
// baseline (521.953 us; speedup 1.0000x reference)
//
#include <hip/hip_runtime.h>
#include <cstdint>
#include <cstddef>

#define Bn 8
#define Nn 2048
#define Fn 64
#define ALPHA 0.2f
#define CAP 256   // per-row CSR capacity: nnz ~ Binom(2048,.05), mean 102, max(16K rows) ~ 145

__device__ __forceinline__ unsigned fkey(float x) {
    unsigned u = __float_as_uint(x);
    return (u & 0x80000000u) ? ~u : (u | 0x80000000u);
}
__device__ __forceinline__ float fdec(unsigned k) {
    return __uint_as_float((k & 0x80000000u) ? (k & 0x7fffffffu) : ~k);
}
__device__ __forceinline__ float lrelu(float x) { return fmaxf(x, ALPHA * x); }

// ---------------- k1: h = input@W, f1 = h@a1, f2 = h@a2, f1max ----------------
__global__ __launch_bounds__(256) void k1_h_f(
        const float* __restrict__ inp, const float* __restrict__ W,
        const float* __restrict__ a1, const float* __restrict__ a2,
        float* __restrict__ h, float* __restrict__ f1, float* __restrict__ f2,
        unsigned* __restrict__ f1key) {
    __shared__ float Wl[Fn * Fn];
    __shared__ float inr[4 * Fn];
    int t = threadIdx.x;
    for (int k = t; k < Fn * Fn; k += 256) Wl[k] = W[k];
    size_t row0 = (size_t)blockIdx.x * 4;
    inr[t] = inp[row0 * Fn + t];
    __syncthreads();
    int r = t >> 6, o = t & 63;
    const float* irow = &inr[r * Fn];
    float acc = 0.f;
#pragma unroll
    for (int f = 0; f < Fn; ++f) acc = fmaf(irow[f], Wl[f * Fn + o], acc);
    size_t row = row0 + r;
    h[row * Fn + o] = acc;
    float p = acc * a1[o];
    float q = acc * a2[o];
#pragma unroll
    for (int off = 32; off > 0; off >>= 1) {
        p += __shfl_down(p, off, 64);
        q += __shfl_down(q, off, 64);
    }
    if (o == 0) {
        f1[row] = p; f2[row] = q;
        atomicMax(&f1key[row >> 11], fkey(p));
    }
}

// ------- k2a: single adj pass -> column D partial sums + per-row CSR lists -------
// grid (Bn, Nn/256 colchunks, 4 rowchunks of 512), block 512 (8 waves share cols, split rows)
__global__ __launch_bounds__(512) void k2a_pass(
        const float* __restrict__ adj, const float* __restrict__ f1,
        const float* __restrict__ f2, const unsigned* __restrict__ f1key,
        float* __restrict__ Dsum, int* __restrict__ cnt,
        unsigned short* __restrict__ idxlist) {
    int b = blockIdx.x;
    int j0 = blockIdx.y * 256;
    int i0 = blockIdx.z * 512;
    int w = threadIdx.x >> 6, lane = threadIdx.x & 63;
    float f1max = fdec(f1key[b]);
    float4 f2v = *(const float4*)&f2[b * Nn + j0 + 4 * lane];
    float Mf0 = fmaxf(lrelu(f1max + f2v.x), 0.f);
    float Mf1 = fmaxf(lrelu(f1max + f2v.y), 0.f);
    float Mf2 = fmaxf(lrelu(f1max + f2v.z), 0.f);
    float Mf3 = fmaxf(lrelu(f1max + f2v.w), 0.f);
    float s0 = 0.f, s1 = 0.f, s2 = 0.f, s3 = 0.f;
    const float* abase = adj + ((size_t)b * Nn) * Nn + j0 + 4 * lane;
    const float* f1b = f1 + b * Nn;
    unsigned long long lt = (1ull << lane) - 1ull;
    int jme = j0 + 4 * lane;

    for (int g = 0; g < 16; ++g) {
        int r0 = i0 + w + 32 * g;
        // prefetch 4 rows (4 KB in flight per wave)
        float4 av0 = *(const float4*)(abase + (size_t)(r0 +  0) * Nn);
        float4 av1 = *(const float4*)(abase + (size_t)(r0 +  8) * Nn);
        float4 av2 = *(const float4*)(abase + (size_t)(r0 + 16) * Nn);
        float4 av3 = *(const float4*)(abase + (size_t)(r0 + 24) * Nn);
        float fi0 = f1b[r0], fi1 = f1b[r0 + 8], fi2 = f1b[r0 + 16], fi3 = f1b[r0 + 24];
#define PROC(AV, FI, IROW)                                                      \
        {                                                                       \
            float x0 = (FI) + f2v.x, x1 = (FI) + f2v.y,                         \
                  x2 = (FI) + f2v.z, x3 = (FI) + f2v.w;                         \
            float l0 = lrelu(x0), l1 = lrelu(x1), l2 = lrelu(x2), l3 = lrelu(x3);\
            bool n0 = AV.x != 0.f, n1 = AV.y != 0.f,                            \
                 n2 = AV.z != 0.f, n3 = AV.w != 0.f;                            \
            s0 += __expf((n0 ? l0 : 0.f) - Mf0);                                \
            s1 += __expf((n1 ? l1 : 0.f) - Mf1);                                \
            s2 += __expf((n2 ? l2 : 0.f) - Mf2);                                \
            s3 += __expf((n3 ? l3 : 0.f) - Mf3);                                \
            unsigned long long m0 = __ballot(n0), m1 = __ballot(n1),            \
                               m2 = __ballot(n2), m3 = __ballot(n3);            \
            int c0 = __popcll(m0), c1 = __popcll(m1),                           \
                c2 = __popcll(m2), c3 = __popcll(m3);                           \
            int tot = c0 + c1 + c2 + c3;                                        \
            if (tot) {                                                          \
                int base = 0;                                                   \
                if (lane == 0) base = atomicAdd(&cnt[b * Nn + (IROW)], tot);    \
                base = __shfl(base, 0, 64);                                     \
                unsigned short* rl = idxlist + ((size_t)(b * Nn + (IROW)) << 8);\
                int p0 = base + __popcll(m0 & lt);                              \
                int p1 = base + c0 + __popcll(m1 & lt);                         \
                int p2 = base + c0 + c1 + __popcll(m2 & lt);                    \
                int p3 = base + c0 + c1 + c2 + __popcll(m3 & lt);               \
                if (n0 && p0 < CAP) rl[p0] = (unsigned short)(jme + 0);         \
                if (n1 && p1 < CAP) rl[p1] = (unsigned short)(jme + 1);         \
                if (n2 && p2 < CAP) rl[p2] = (unsigned short)(jme + 2);         \
                if (n3 && p3 < CAP) rl[p3] = (unsigned short)(jme + 3);         \
            }                                                                   \
        }
        PROC(av0, fi0, r0 +  0)
        PROC(av1, fi1, r0 +  8)
        PROC(av2, fi2, r0 + 16)
        PROC(av3, fi3, r0 + 24)
#undef PROC
    }
    // cross-wave column reduction -> atomicAdd into Dsum
    __shared__ float sred[8][256];
    sred[w][4 * lane + 0] = s0;
    sred[w][4 * lane + 1] = s1;
    sred[w][4 * lane + 2] = s2;
    sred[w][4 * lane + 3] = s3;
    __syncthreads();
    if (threadIdx.x < 256) {
        int c = threadIdx.x;
        float v = 0.f;
#pragma unroll
        for (int k = 0; k < 8; ++k) v += sred[k][c];
        atomicAdd(&Dsum[b * Nn + j0 + c], v);
    }
}

// ------- k2b: finalize per-column stats (Mf,R,z,f2) + hz = sum_j z_j*h[j,:] -------
// grid (Bn, 4), block 256
__global__ __launch_bounds__(256) void k2b_finalize(
        const float* __restrict__ Dsum, const float* __restrict__ f2,
        const unsigned* __restrict__ f1key, const float* __restrict__ h,
        float4* __restrict__ cs, float* __restrict__ hz) {
    int b = blockIdx.x;
    int jbase = blockIdx.y * 512;
    int t = threadIdx.x;
    float f1max = fdec(f1key[b]);
    __shared__ float zsh[512];
    for (int jj = t; jj < 512; jj += 256) {
        int j = jbase + jj;
        float f2j = f2[b * Nn + j];
        float Mf = fmaxf(lrelu(f1max + f2j), 0.f);
        float R = 1.f / Dsum[b * Nn + j];
        float z = __expf(-Mf) * R;
        cs[b * Nn + j] = make_float4(Mf, R, z, f2j);
        zsh[jj] = z;
    }
    __syncthreads();
    int w = t >> 6, lane = t & 63;
    float acc = 0.f;
#pragma unroll 4
    for (int jj = w; jj < 512; jj += 4)
        acc = fmaf(zsh[jj], h[((size_t)(b * Nn + jbase + jj)) * Fn + lane], acc);
    __shared__ float hred[4][64];
    hred[w][lane] = acc;
    __syncthreads();
    if (w == 0) {
        float v = hred[0][lane] + hred[1][lane] + hred[2][lane] + hred[3][lane];
        atomicAdd(&hz[b * Fn + lane], v);
    }
}

// ------- k3: sparse aggregation via CSR lists + epilogue -------
// grid (Bn, Nn/4), block 256 (one wave per output row)
__global__ __launch_bounds__(256) void k3_aggregate(
        const unsigned short* __restrict__ idxlist, const int* __restrict__ cnt,
        const float* __restrict__ f1, const float4* __restrict__ cs,
        const float* __restrict__ h, const float* __restrict__ hz,
        const float* __restrict__ inp, const float* __restrict__ bias,
        float* __restrict__ out) {
    int b = blockIdx.x;
    int w = threadIdx.x >> 6, lane = threadIdx.x & 63;
    int i = blockIdx.y * 4 + w;
    int row = b * Nn + i;
    int n = min(cnt[row], CAP);
    float f1i = f1[row];
    const unsigned short* rl = idxlist + ((size_t)row << 8);
    const float4* csb = cs + (size_t)b * Nn;
    const float* hb = h + (size_t)b * Nn * Fn;
    float acc0 = hz[b * Fn + lane], acc1 = 0.f;
    int t = 0;
    for (; t + 4 <= n; t += 4) {
        int j0 = rl[t], j1 = rl[t + 1], j2 = rl[t + 2], j3 = rl[t + 3];
        float4 c0 = csb[j0], c1 = csb[j1], c2 = csb[j2], c3 = csb[j3];
        float k0 = __expf(lrelu(f1i + c0.w) - c0.x) * c0.y - c0.z;
        float k1 = __expf(lrelu(f1i + c1.w) - c1.x) * c1.y - c1.z;
        float k2 = __expf(lrelu(f1i + c2.w) - c2.x) * c2.y - c2.z;
        float k3 = __expf(lrelu(f1i + c3.w) - c3.x) * c3.y - c3.z;
        acc0 = fmaf(k0, hb[(size_t)j0 * Fn + lane], acc0);
        acc1 = fmaf(k1, hb[(size_t)j1 * Fn + lane], acc1);
        acc0 = fmaf(k2, hb[(size_t)j2 * Fn + lane], acc0);
        acc1 = fmaf(k3, hb[(size_t)j3 * Fn + lane], acc1);
    }
    for (; t < n; ++t) {
        int j = rl[t];
        float4 c = csb[j];
        float k = __expf(lrelu(f1i + c.w) - c.x) * c.y - c.z;
        acc0 = fmaf(k, hb[(size_t)j * Fn + lane], acc0);
    }
    float acc = acc0 + acc1;
    size_t idx = (size_t)row * Fn + lane;
    float hp = acc + bias[i * Fn + lane] + inp[idx];
    out[idx] = hp > 0.f ? hp : __expf(hp) - 1.f;
}

extern "C" void kernel_launch(void* const* d_in, const int* in_sizes, int n_in,
                              void* d_out, int out_size, void* d_ws, size_t ws_size,
                              hipStream_t stream) {
    const float* inp  = (const float*)d_in[0];
    const float* adj  = (const float*)d_in[1];
    const float* W    = (const float*)d_in[2];
    const float* a1   = (const float*)d_in[3];
    const float* a2   = (const float*)d_in[4];
    const float* bias = (const float*)d_in[5];
    float* out = (float*)d_out;

    // workspace layout
    float* h      = (float*)d_ws;                         // 8*2048*64 floats = 4 MB
    float4* cs    = (float4*)(h + (size_t)Bn * Nn * Fn);  // 16384 float4 = 256 KB
    float* f1     = (float*)(cs + (size_t)Bn * Nn);       // 64 KB
    float* f2     = f1 + (size_t)Bn * Nn;                 // 64 KB
    float* hz     = f2 + (size_t)Bn * Nn;                 // 2 KB   (zeroed)
    float* Dsum   = hz + (size_t)Bn * Fn;                 // 64 KB  (zeroed)
    int*   cnt    = (int*)(Dsum + (size_t)Bn * Nn);       // 64 KB  (zeroed)
    unsigned* f1key = (unsigned*)(cnt + (size_t)Bn * Nn); // 64 B   (zeroed)
    unsigned short* idxlist = (unsigned short*)(f1key + 16); // 8*2048*256*2 = 8 MB

    size_t zbytes = (size_t)Bn * Fn * 4 + (size_t)Bn * Nn * 4 * 2 + 64;
    hipMemsetAsync(hz, 0, zbytes, stream);
    k1_h_f<<<Bn * Nn / 4, 256, 0, stream>>>(inp, W, a1, a2, h, f1, f2, f1key);
    k2a_pass<<<dim3(Bn, Nn / 256, 4), 512, 0, stream>>>(adj, f1, f2, f1key, Dsum, cnt, idxlist);
    k2b_finalize<<<dim3(Bn, 4), 256, 0, stream>>>(Dsum, f2, f1key, h, cs, hz);
    k3_aggregate<<<dim3(Bn, Nn / 4), 256, 0, stream>>>(idxlist, cnt, f1, cs, h, hz, inp, bias, out);
}

// Round 3
// 343.903 us; speedup vs baseline: 1.5177x; 1.5177x over previous
//
#include <hip/hip_runtime.h>
#include <cstdint>
#include <cstddef>

#define Bn 8
#define Nn 2048
#define Fn 64
#define ALPHA 0.2f

__device__ __forceinline__ float lrelu(float x) { return fmaxf(x, ALPHA * x); }

// ---------------- k1: h = input@W, f1 = h@a1, f2 = h@a2 ----------------
// grid B*N/4, block 256 (one wave per row). No atomics.
__global__ __launch_bounds__(256) void k1_h_f(
        const float* __restrict__ inp, const float* __restrict__ W,
        const float* __restrict__ a1, const float* __restrict__ a2,
        float* __restrict__ h, float* __restrict__ f1, float* __restrict__ f2) {
    __shared__ float Wl[Fn * Fn];
    __shared__ float inr[4 * Fn];
    int t = threadIdx.x;
    for (int k = t; k < Fn * Fn; k += 256) Wl[k] = W[k];
    size_t row0 = (size_t)blockIdx.x * 4;
    inr[t] = inp[row0 * Fn + t];
    __syncthreads();
    int r = t >> 6, o = t & 63;
    const float* irow = &inr[r * Fn];
    float acc = 0.f;
#pragma unroll
    for (int f = 0; f < Fn; ++f) acc = fmaf(irow[f], Wl[f * Fn + o], acc);
    size_t row = row0 + r;
    h[row * Fn + o] = acc;
    float p = acc * a1[o];
    float q = acc * a2[o];
#pragma unroll
    for (int off = 32; off > 0; off >>= 1) {
        p += __shfl_down(p, off, 64);
        q += __shfl_down(q, off, 64);
    }
    if (o == 0) { f1[row] = p; f2[row] = q; }
}

// ---------------- k1b: f1max[b] = max_i f1[b,i] (tiny reduction) ----------------
__global__ __launch_bounds__(256) void k1b_max(
        const float* __restrict__ f1, float* __restrict__ f1max) {
    int b = blockIdx.x, t = threadIdx.x;
    float m = -3.4e38f;
    for (int i = t; i < Nn; i += 256) m = fmaxf(m, f1[b * Nn + i]);
#pragma unroll
    for (int off = 32; off > 0; off >>= 1) m = fmaxf(m, __shfl_down(m, off, 64));
    __shared__ float sm[4];
    if ((t & 63) == 0) sm[t >> 6] = m;
    __syncthreads();
    if (t == 0) f1max[b] = fmaxf(fmaxf(sm[0], sm[1]), fmaxf(sm[2], sm[3]));
}

// ------- k2a: single adj pass -> column D partials + per-(row,chunk) CSR slices -------
// grid (Bn, 8 col-chunks of 256, 4 row-chunks of 512), block 512.
// Each (row, chunk) visited by exactly ONE wave -> compaction needs no atomics.
__global__ __launch_bounds__(512) void k2a_pass(
        const float* __restrict__ adj, const float* __restrict__ f1,
        const float* __restrict__ f2, const float* __restrict__ f1max_p,
        float* __restrict__ Dsum, unsigned short* __restrict__ cnt8,
        unsigned short* __restrict__ idxlist, int slice) {
    int b = blockIdx.x;
    int cj = blockIdx.y;
    int j0 = cj * 256;
    int i0 = blockIdx.z * 512;
    int w = threadIdx.x >> 6, lane = threadIdx.x & 63;
    float f1max = f1max_p[b];
    float4 f2v = *(const float4*)&f2[b * Nn + j0 + 4 * lane];
    float Mf0 = fmaxf(lrelu(f1max + f2v.x), 0.f);
    float Mf1 = fmaxf(lrelu(f1max + f2v.y), 0.f);
    float Mf2 = fmaxf(lrelu(f1max + f2v.z), 0.f);
    float Mf3 = fmaxf(lrelu(f1max + f2v.w), 0.f);
    float s0 = 0.f, s1 = 0.f, s2 = 0.f, s3 = 0.f;
    const float* abase = adj + ((size_t)b * Nn) * Nn + j0 + 4 * lane;
    const float* f1b = f1 + b * Nn;
    unsigned long long lt = (1ull << lane) - 1ull;
    int jme = j0 + 4 * lane;

    for (int g = 0; g < 16; ++g) {
        int r0 = i0 + w + 32 * g;
        float4 av0 = *(const float4*)(abase + (size_t)(r0 +  0) * Nn);
        float4 av1 = *(const float4*)(abase + (size_t)(r0 +  8) * Nn);
        float4 av2 = *(const float4*)(abase + (size_t)(r0 + 16) * Nn);
        float4 av3 = *(const float4*)(abase + (size_t)(r0 + 24) * Nn);
        float fi0 = f1b[r0], fi1 = f1b[r0 + 8], fi2 = f1b[r0 + 16], fi3 = f1b[r0 + 24];
#define PROC(AV, FI, IROW)                                                       \
        {                                                                        \
            float x0 = (FI) + f2v.x, x1 = (FI) + f2v.y,                          \
                  x2 = (FI) + f2v.z, x3 = (FI) + f2v.w;                          \
            float l0 = lrelu(x0), l1 = lrelu(x1), l2 = lrelu(x2), l3 = lrelu(x3);\
            bool n0 = AV.x != 0.f, n1 = AV.y != 0.f,                             \
                 n2 = AV.z != 0.f, n3 = AV.w != 0.f;                             \
            s0 += __expf((n0 ? l0 : 0.f) - Mf0);                                 \
            s1 += __expf((n1 ? l1 : 0.f) - Mf1);                                 \
            s2 += __expf((n2 ? l2 : 0.f) - Mf2);                                 \
            s3 += __expf((n3 ? l3 : 0.f) - Mf3);                                 \
            unsigned long long m0 = __ballot(n0), m1 = __ballot(n1),             \
                               m2 = __ballot(n2), m3 = __ballot(n3);             \
            int c0 = __popcll(m0), c1 = __popcll(m1),                            \
                c2 = __popcll(m2), c3 = __popcll(m3);                            \
            int tot = c0 + c1 + c2 + c3;                                         \
            if (tot) {                                                           \
                unsigned short* rl = idxlist +                                   \
                    (size_t)(((b * Nn + (IROW)) << 3) + cj) * slice;             \
                int p0 = __popcll(m0 & lt);                                      \
                int p1 = c0 + __popcll(m1 & lt);                                 \
                int p2 = c0 + c1 + __popcll(m2 & lt);                            \
                int p3 = c0 + c1 + c2 + __popcll(m3 & lt);                       \
                if (n0 && p0 < slice) rl[p0] = (unsigned short)(jme + 0);        \
                if (n1 && p1 < slice) rl[p1] = (unsigned short)(jme + 1);        \
                if (n2 && p2 < slice) rl[p2] = (unsigned short)(jme + 2);        \
                if (n3 && p3 < slice) rl[p3] = (unsigned short)(jme + 3);        \
            }                                                                    \
            if (lane == 0)                                                       \
                cnt8[((b * Nn + (IROW)) << 3) + cj] =                            \
                    (unsigned short)(tot < slice ? tot : slice);                 \
        }
        PROC(av0, fi0, r0 +  0)
        PROC(av1, fi1, r0 +  8)
        PROC(av2, fi2, r0 + 16)
        PROC(av3, fi3, r0 + 24)
#undef PROC
    }
    __shared__ float sred[8][256];
    sred[w][4 * lane + 0] = s0;
    sred[w][4 * lane + 1] = s1;
    sred[w][4 * lane + 2] = s2;
    sred[w][4 * lane + 3] = s3;
    __syncthreads();
    if (threadIdx.x < 256) {
        int c = threadIdx.x;
        float v = 0.f;
#pragma unroll
        for (int k = 0; k < 8; ++k) v += sred[k][c];
        atomicAdd(&Dsum[b * Nn + j0 + c], v);
    }
}

// ------- k2b: finalize per-column stats (Mf,R,z,f2) + hz = sum_j z_j*h[j,:] -------
__global__ __launch_bounds__(256) void k2b_finalize(
        const float* __restrict__ Dsum, const float* __restrict__ f2,
        const float* __restrict__ f1max_p, const float* __restrict__ h,
        float4* __restrict__ cs, float* __restrict__ hz) {
    int b = blockIdx.x;
    int jbase = blockIdx.y * 512;
    int t = threadIdx.x;
    float f1max = f1max_p[b];
    __shared__ float zsh[512];
    for (int jj = t; jj < 512; jj += 256) {
        int j = jbase + jj;
        float f2j = f2[b * Nn + j];
        float Mf = fmaxf(lrelu(f1max + f2j), 0.f);
        float R = 1.f / Dsum[b * Nn + j];
        float z = __expf(-Mf) * R;
        cs[b * Nn + j] = make_float4(Mf, R, z, f2j);
        zsh[jj] = z;
    }
    __syncthreads();
    int w = t >> 6, lane = t & 63;
    float acc = 0.f;
#pragma unroll 4
    for (int jj = w; jj < 512; jj += 4)
        acc = fmaf(zsh[jj], h[((size_t)(b * Nn + jbase + jj)) * Fn + lane], acc);
    __shared__ float hred[4][64];
    hred[w][lane] = acc;
    __syncthreads();
    if (w == 0) {
        float v = hred[0][lane] + hred[1][lane] + hred[2][lane] + hred[3][lane];
        atomicAdd(&hz[b * Fn + lane], v);
    }
}

// ------- k3: sparse aggregation via per-chunk CSR slices + epilogue -------
// grid (Bn, Nn/4), block 256 (one wave per output row).
__global__ __launch_bounds__(256) void k3_aggregate(
        const unsigned short* __restrict__ idxlist,
        const unsigned short* __restrict__ cnt8,
        const float* __restrict__ f1, const float4* __restrict__ cs,
        const float* __restrict__ h, const float* __restrict__ hz,
        const float* __restrict__ inp, const float* __restrict__ bias,
        float* __restrict__ out, int slice) {
    int b = blockIdx.x;
    int w = threadIdx.x >> 6, lane = threadIdx.x & 63;
    int i = blockIdx.y * 4 + w;
    int row = b * Nn + i;
    float f1i = f1[row];
    const float4* csb = cs + (size_t)b * Nn;
    const float* hb = h + (size_t)b * Nn * Fn;
    float acc0 = hz[b * Fn + lane], acc1 = 0.f;
    for (int cj = 0; cj < 8; ++cj) {
        int n = cnt8[(row << 3) + cj];
        const unsigned short* rl = idxlist + (size_t)((row << 3) + cj) * slice;
        int t = 0;
        for (; t + 4 <= n; t += 4) {
            int j0 = rl[t], j1 = rl[t + 1], j2 = rl[t + 2], j3 = rl[t + 3];
            float4 c0 = csb[j0], c1 = csb[j1], c2 = csb[j2], c3 = csb[j3];
            float k0 = __expf(lrelu(f1i + c0.w) - c0.x) * c0.y - c0.z;
            float k1 = __expf(lrelu(f1i + c1.w) - c1.x) * c1.y - c1.z;
            float k2 = __expf(lrelu(f1i + c2.w) - c2.x) * c2.y - c2.z;
            float k3 = __expf(lrelu(f1i + c3.w) - c3.x) * c3.y - c3.z;
            acc0 = fmaf(k0, hb[(size_t)j0 * Fn + lane], acc0);
            acc1 = fmaf(k1, hb[(size_t)j1 * Fn + lane], acc1);
            acc0 = fmaf(k2, hb[(size_t)j2 * Fn + lane], acc0);
            acc1 = fmaf(k3, hb[(size_t)j3 * Fn + lane], acc1);
        }
        for (; t < n; ++t) {
            int j = rl[t];
            float4 c = csb[j];
            float k = __expf(lrelu(f1i + c.w) - c.x) * c.y - c.z;
            acc0 = fmaf(k, hb[(size_t)j * Fn + lane], acc0);
        }
    }
    float acc = acc0 + acc1;
    size_t idx = (size_t)row * Fn + lane;
    float hp = acc + bias[i * Fn + lane] + inp[idx];
    out[idx] = hp > 0.f ? hp : __expf(hp) - 1.f;
}

extern "C" void kernel_launch(void* const* d_in, const int* in_sizes, int n_in,
                              void* d_out, int out_size, void* d_ws, size_t ws_size,
                              hipStream_t stream) {
    const float* inp  = (const float*)d_in[0];
    const float* adj  = (const float*)d_in[1];
    const float* W    = (const float*)d_in[2];
    const float* a1   = (const float*)d_in[3];
    const float* a2   = (const float*)d_in[4];
    const float* bias = (const float*)d_in[5];
    float* out = (float*)d_out;

    // workspace layout
    float* h      = (float*)d_ws;                          // 4 MB
    float4* cs    = (float4*)(h + (size_t)Bn * Nn * Fn);   // 256 KB
    float* f1     = (float*)(cs + (size_t)Bn * Nn);        // 64 KB
    float* f2     = f1 + (size_t)Bn * Nn;                  // 64 KB
    float* hz     = f2 + (size_t)Bn * Nn;                  // 2 KB   (zeroed)
    float* Dsum   = hz + (size_t)Bn * Fn;                  // 64 KB  (zeroed, contiguous w/ hz)
    float* f1max  = Dsum + (size_t)Bn * Nn;                // 64 B
    unsigned short* cnt8 = (unsigned short*)(f1max + 16);  // 256 KB
    unsigned short* idxlist = cnt8 + (size_t)Bn * Nn * 8;  // Bn*Nn*8*slice ushort

    size_t fixed = (size_t)((char*)idxlist - (char*)d_ws);
    size_t cap = (ws_size > fixed) ? (ws_size - fixed) / ((size_t)Bn * Nn * 8 * 2) : 0;
    int slice = (cap >= 64) ? 64 : (cap >= 48 ? 48 : 32);  // nnz/chunk ~ Binom(256,.05): mean 12.8

    hipMemsetAsync(hz, 0, ((size_t)Bn * Fn + (size_t)Bn * Nn) * sizeof(float), stream);
    k1_h_f<<<Bn * Nn / 4, 256, 0, stream>>>(inp, W, a1, a2, h, f1, f2);
    k1b_max<<<Bn, 256, 0, stream>>>(f1, f1max);
    k2a_pass<<<dim3(Bn, 8, 4), 512, 0, stream>>>(adj, f1, f2, f1max, Dsum, cnt8, idxlist, slice);
    k2b_finalize<<<dim3(Bn, 4), 256, 0, stream>>>(Dsum, f2, f1max, h, cs, hz);
    k3_aggregate<<<dim3(Bn, Nn / 4), 256, 0, stream>>>(idxlist, cnt8, f1, cs, h, hz, inp, bias, out, slice);
}

// Round 4
// 298.148 us; speedup vs baseline: 1.7506x; 1.1535x over previous
//
#include <hip/hip_runtime.h>
#include <cstdint>
#include <cstddef>

#define Bn 8
#define Nn 2048
#define Fn 64
#define ALPHA 0.2f

__device__ __forceinline__ float lrelu(float x) { return fmaxf(x, ALPHA * x); }

// ---------------- k1: h = input@W, f1 = h@a1, f2 = h@a2 ----------------
__global__ __launch_bounds__(256) void k1_h_f(
        const float* __restrict__ inp, const float* __restrict__ W,
        const float* __restrict__ a1, const float* __restrict__ a2,
        float* __restrict__ h, float* __restrict__ f1, float* __restrict__ f2) {
    __shared__ float Wl[Fn * Fn];
    __shared__ float inr[4 * Fn];
    int t = threadIdx.x;
    for (int k = t; k < Fn * Fn; k += 256) Wl[k] = W[k];
    size_t row0 = (size_t)blockIdx.x * 4;
    inr[t] = inp[row0 * Fn + t];
    __syncthreads();
    int r = t >> 6, o = t & 63;
    const float* irow = &inr[r * Fn];
    float acc = 0.f;
#pragma unroll
    for (int f = 0; f < Fn; ++f) acc = fmaf(irow[f], Wl[f * Fn + o], acc);
    size_t row = row0 + r;
    h[row * Fn + o] = acc;
    float p = acc * a1[o];
    float q = acc * a2[o];
#pragma unroll
    for (int off = 32; off > 0; off >>= 1) {
        p += __shfl_down(p, off, 64);
        q += __shfl_down(q, off, 64);
    }
    if (o == 0) { f1[row] = p; f2[row] = q; }
}

// ---------------- k1b: f1max[b] = max_i f1[b,i] ----------------
__global__ __launch_bounds__(256) void k1b_max(
        const float* __restrict__ f1, float* __restrict__ f1max) {
    int b = blockIdx.x, t = threadIdx.x;
    float m = -3.4e38f;
    for (int i = t; i < Nn; i += 256) m = fmaxf(m, f1[b * Nn + i]);
#pragma unroll
    for (int off = 32; off > 0; off >>= 1) m = fmaxf(m, __shfl_down(m, off, 64));
    __shared__ float sm[4];
    if ((t & 63) == 0) sm[t >> 6] = m;
    __syncthreads();
    if (t == 0) f1max[b] = fmaxf(fmaxf(sm[0], sm[1]), fmaxf(sm[2], sm[3]));
}

// ------- k2a: single adj pass -> column D partials + per-(row,chunk) value records -------
// grid (Bn, 8 col-chunks of 256, 16 row-chunks of 128), block 512.
// Each (row, chunk) visited by exactly ONE wave -> atomic-free compaction.
// record = (col_idx << 16) | bf16(exp(l - Mf_col))
__global__ __launch_bounds__(512) void k2a_pass(
        const float* __restrict__ adj, const float* __restrict__ f1,
        const float* __restrict__ f2, const float* __restrict__ f1max_p,
        float* __restrict__ Dsum, unsigned short* __restrict__ cnt8,
        unsigned* __restrict__ records, int slice) {
    int b = blockIdx.x;
    int cj = blockIdx.y;
    int j0 = cj * 256;
    int i0 = blockIdx.z * 128;
    int w = threadIdx.x >> 6, lane = threadIdx.x & 63;
    float f1max = f1max_p[b];
    float4 f2v = *(const float4*)&f2[b * Nn + j0 + 4 * lane];
    float Mf0 = fmaxf(lrelu(f1max + f2v.x), 0.f);
    float Mf1 = fmaxf(lrelu(f1max + f2v.y), 0.f);
    float Mf2 = fmaxf(lrelu(f1max + f2v.z), 0.f);
    float Mf3 = fmaxf(lrelu(f1max + f2v.w), 0.f);
    float s0 = 0.f, s1 = 0.f, s2 = 0.f, s3 = 0.f;
    const float* abase = adj + ((size_t)b * Nn) * Nn + j0 + 4 * lane;
    const float* f1b = f1 + b * Nn;
    unsigned long long lt = (1ull << lane) - 1ull;
    unsigned jme = (unsigned)(j0 + 4 * lane) << 16;

    for (int g = 0; g < 4; ++g) {
        int r0 = i0 + w + 32 * g;
        float4 av0 = *(const float4*)(abase + (size_t)(r0 +  0) * Nn);
        float4 av1 = *(const float4*)(abase + (size_t)(r0 +  8) * Nn);
        float4 av2 = *(const float4*)(abase + (size_t)(r0 + 16) * Nn);
        float4 av3 = *(const float4*)(abase + (size_t)(r0 + 24) * Nn);
        float fi0 = f1b[r0], fi1 = f1b[r0 + 8], fi2 = f1b[r0 + 16], fi3 = f1b[r0 + 24];
#define PROC(AV, FI, IROW)                                                       \
        {                                                                        \
            bool n0 = AV.x != 0.f, n1 = AV.y != 0.f,                             \
                 n2 = AV.z != 0.f, n3 = AV.w != 0.f;                             \
            float e0 = __expf((n0 ? lrelu((FI) + f2v.x) : 0.f) - Mf0);           \
            float e1 = __expf((n1 ? lrelu((FI) + f2v.y) : 0.f) - Mf1);           \
            float e2 = __expf((n2 ? lrelu((FI) + f2v.z) : 0.f) - Mf2);           \
            float e3 = __expf((n3 ? lrelu((FI) + f2v.w) : 0.f) - Mf3);           \
            s0 += e0; s1 += e1; s2 += e2; s3 += e3;                              \
            unsigned long long m0 = __ballot(n0), m1 = __ballot(n1),             \
                               m2 = __ballot(n2), m3 = __ballot(n3);             \
            int c0 = __popcll(m0), c1 = __popcll(m1),                            \
                c2 = __popcll(m2), c3 = __popcll(m3);                            \
            int tot = c0 + c1 + c2 + c3;                                         \
            if (tot) {                                                           \
                unsigned* rl = records +                                         \
                    (size_t)(((b * Nn + (IROW)) << 3) + cj) * slice;             \
                int p0 = __popcll(m0 & lt);                                      \
                int p1 = c0 + __popcll(m1 & lt);                                 \
                int p2 = c0 + c1 + __popcll(m2 & lt);                            \
                int p3 = c0 + c1 + c2 + __popcll(m3 & lt);                       \
                if (n0 && p0 < slice)                                            \
                    rl[p0] = (jme + 0x00000) | (__float_as_uint(e0) >> 16);      \
                if (n1 && p1 < slice)                                            \
                    rl[p1] = (jme + 0x10000) | (__float_as_uint(e1) >> 16);      \
                if (n2 && p2 < slice)                                            \
                    rl[p2] = (jme + 0x20000) | (__float_as_uint(e2) >> 16);      \
                if (n3 && p3 < slice)                                            \
                    rl[p3] = (jme + 0x30000) | (__float_as_uint(e3) >> 16);      \
            }                                                                    \
            if (lane == 0)                                                       \
                cnt8[((b * Nn + (IROW)) << 3) + cj] =                            \
                    (unsigned short)(tot < slice ? tot : slice);                 \
        }
        PROC(av0, fi0, r0 +  0)
        PROC(av1, fi1, r0 +  8)
        PROC(av2, fi2, r0 + 16)
        PROC(av3, fi3, r0 + 24)
#undef PROC
    }
    __shared__ float sred[8][256];
    sred[w][4 * lane + 0] = s0;
    sred[w][4 * lane + 1] = s1;
    sred[w][4 * lane + 2] = s2;
    sred[w][4 * lane + 3] = s3;
    __syncthreads();
    if (threadIdx.x < 256) {
        int c = threadIdx.x;
        float v = 0.f;
#pragma unroll
        for (int k = 0; k < 8; ++k) v += sred[k][c];
        atomicAdd(&Dsum[b * Nn + j0 + c], v);
    }
}

// ------- k2b: per-column {R = 1/D, z = exp(-Mf)*R} + hz = sum_j z_j*h[j,:] -------
// grid (Bn, 16), block 256; 128 columns per block
__global__ __launch_bounds__(256) void k2b_finalize(
        const float* __restrict__ Dsum, const float* __restrict__ f2,
        const float* __restrict__ f1max_p, const float* __restrict__ h,
        float2* __restrict__ cs, float* __restrict__ hz) {
    int b = blockIdx.x;
    int jbase = blockIdx.y * 128;
    int t = threadIdx.x;
    float f1max = f1max_p[b];
    __shared__ float zsh[128];
    if (t < 128) {
        int j = jbase + t;
        float f2j = f2[b * Nn + j];
        float Mf = fmaxf(lrelu(f1max + f2j), 0.f);
        float R = 1.f / Dsum[b * Nn + j];
        float z = __expf(-Mf) * R;
        cs[b * Nn + j] = make_float2(R, z);
        zsh[t] = z;
    }
    __syncthreads();
    int w = t >> 6, lane = t & 63;
    float acc = 0.f;
#pragma unroll 4
    for (int jj = w; jj < 128; jj += 4)
        acc = fmaf(zsh[jj], h[((size_t)(b * Nn + jbase + jj)) * Fn + lane], acc);
    __shared__ float hred[4][64];
    hred[w][lane] = acc;
    __syncthreads();
    if (w == 0) {
        float v = hred[0][lane] + hred[1][lane] + hred[2][lane] + hred[3][lane];
        atomicAdd(&hz[b * Fn + lane], v);
    }
}

// ------- k3: sparse aggregation, cooperative record processing + epilogue -------
// grid (Bn, Nn/4), block 256 (one wave per output row).
__global__ __launch_bounds__(256) void k3_aggregate(
        const unsigned* __restrict__ records,
        const unsigned short* __restrict__ cnt8,
        const float2* __restrict__ cs,
        const float* __restrict__ h, const float* __restrict__ hz,
        const float* __restrict__ inp, const float* __restrict__ bias,
        float* __restrict__ out, int slice) {
    int b = blockIdx.x;
    int w = threadIdx.x >> 6, lane = threadIdx.x & 63;
    int i = blockIdx.y * 4 + w;
    int row = b * Nn + i;
    const float2* csb = cs + (size_t)b * Nn;
    const float* hb = h + (size_t)b * Nn * Fn;
    const unsigned* rb = records + (size_t)(row << 3) * slice;

    // 8 chunk counts: one 16B load
    uint4 cw = *(const uint4*)(cnt8 + (row << 3));
    int nc[8] = { (int)(cw.x & 0xffff), (int)(cw.x >> 16),
                  (int)(cw.y & 0xffff), (int)(cw.y >> 16),
                  (int)(cw.z & 0xffff), (int)(cw.z >> 16),
                  (int)(cw.w & 0xffff), (int)(cw.w >> 16) };

    // preload all 8 record slots for this lane (independent loads in flight)
    unsigned recs[8];
#pragma unroll
    for (int cj = 0; cj < 8; ++cj) recs[cj] = rb[slice * cj + lane];

    // per-lane coefficient: coef = val * R_j - z_j  (parallel cs gathers)
    int idxs[8];
    float coefs[8];
#pragma unroll
    for (int cj = 0; cj < 8; ++cj) {
        idxs[cj] = (int)((recs[cj] >> 16) & 2047);
        float val = __uint_as_float(recs[cj] << 16);
        float2 rz = csb[idxs[cj]];
        coefs[cj] = fmaf(val, rz.x, -rz.y);
    }

    float acc = hz[b * Fn + lane];
#pragma unroll
    for (int cj = 0; cj < 8; ++cj) {
        int n = nc[cj];
        for (int k = 0; k < n; ++k) {
            float c = __shfl(coefs[cj], k, 64);
            int j = __shfl(idxs[cj], k, 64);
            acc = fmaf(c, hb[(size_t)j * Fn + lane], acc);
        }
    }
    size_t idxo = (size_t)row * Fn + lane;
    float hp = acc + bias[i * Fn + lane] + inp[idxo];
    out[idxo] = hp > 0.f ? hp : __expf(hp) - 1.f;
}

extern "C" void kernel_launch(void* const* d_in, const int* in_sizes, int n_in,
                              void* d_out, int out_size, void* d_ws, size_t ws_size,
                              hipStream_t stream) {
    const float* inp  = (const float*)d_in[0];
    const float* adj  = (const float*)d_in[1];
    const float* W    = (const float*)d_in[2];
    const float* a1   = (const float*)d_in[3];
    const float* a2   = (const float*)d_in[4];
    const float* bias = (const float*)d_in[5];
    float* out = (float*)d_out;

    // workspace layout (all sections 64B-multiple)
    float* h      = (float*)d_ws;                          // 4 MB
    float2* cs    = (float2*)(h + (size_t)Bn * Nn * Fn);   // 128 KB
    float* f1     = (float*)(cs + (size_t)Bn * Nn);        // 64 KB
    float* f2     = f1 + (size_t)Bn * Nn;                  // 64 KB
    float* hz     = f2 + (size_t)Bn * Nn;                  // 2 KB   (zeroed)
    float* Dsum   = hz + (size_t)Bn * Fn;                  // 64 KB  (zeroed, contiguous)
    float* f1max  = Dsum + (size_t)Bn * Nn;                // 64 B
    unsigned short* cnt8 = (unsigned short*)(f1max + 16);  // 256 KB
    unsigned* records = (unsigned*)(cnt8 + (size_t)Bn * Nn * 8);

    size_t fixed = (size_t)((char*)records - (char*)d_ws) + 512; // +tail pad for lane over-read
    size_t cap = (ws_size > fixed) ? (ws_size - fixed) / ((size_t)Bn * Nn * 8 * 4) : 0;
    int slice = (cap >= 48) ? 48 : (cap >= 32 ? 32 : 24); // nnz/chunk ~ Binom(256,.05): mean 12.8

    hipMemsetAsync(hz, 0, ((size_t)Bn * Fn + (size_t)Bn * Nn) * sizeof(float), stream);
    k1_h_f<<<Bn * Nn / 4, 256, 0, stream>>>(inp, W, a1, a2, h, f1, f2);
    k1b_max<<<Bn, 256, 0, stream>>>(f1, f1max);
    k2a_pass<<<dim3(Bn, 8, 16), 512, 0, stream>>>(adj, f1, f2, f1max, Dsum, cnt8, records, slice);
    k2b_finalize<<<dim3(Bn, 16), 256, 0, stream>>>(Dsum, f2, f1max, h, cs, hz);
    k3_aggregate<<<dim3(Bn, Nn / 4), 256, 0, stream>>>(records, cnt8, cs, h, hz, inp, bias, out, slice);
}

// Round 5
// 277.102 us; speedup vs baseline: 1.8836x; 1.0760x over previous
//
#include <hip/hip_runtime.h>
#include <cstdint>
#include <cstddef>

#define Bn 8
#define Nn 2048
#define Fn 64
#define ALPHA 0.2f

typedef __attribute__((ext_vector_type(8))) short  s8frag;   // 8 x bf16
typedef __attribute__((ext_vector_type(4))) float  f4frag;   // 4 x f32 acc

__device__ __forceinline__ float lrelu(float x) { return fmaxf(x, ALPHA * x); }
__device__ __forceinline__ float elu(float x)   { return x > 0.f ? x : __expf(x) - 1.f; }
// f32 -> bf16 round-to-nearest-even-ish (values are positive finite here)
__device__ __forceinline__ unsigned short bfr(float f) {
    unsigned u = __float_as_uint(f);
    u += 0x7fffu + ((u >> 16) & 1u);
    return (unsigned short)(u >> 16);
}

// ---------------- k1: h = input@W, f1 = h@a1, f2 = h@a2 ----------------
__global__ __launch_bounds__(256) void k1_h_f(
        const float* __restrict__ inp, const float* __restrict__ W,
        const float* __restrict__ a1, const float* __restrict__ a2,
        float* __restrict__ h, float* __restrict__ f1, float* __restrict__ f2) {
    __shared__ float Wl[Fn * Fn];
    __shared__ float inr[4 * Fn];
    int t = threadIdx.x;
    for (int k = t; k < Fn * Fn; k += 256) Wl[k] = W[k];
    size_t row0 = (size_t)blockIdx.x * 4;
    inr[t] = inp[row0 * Fn + t];
    __syncthreads();
    int r = t >> 6, o = t & 63;
    const float* irow = &inr[r * Fn];
    float acc = 0.f;
#pragma unroll
    for (int f = 0; f < Fn; ++f) acc = fmaf(irow[f], Wl[f * Fn + o], acc);
    size_t row = row0 + r;
    h[row * Fn + o] = acc;
    float p = acc * a1[o];
    float q = acc * a2[o];
#pragma unroll
    for (int off = 32; off > 0; off >>= 1) {
        p += __shfl_down(p, off, 64);
        q += __shfl_down(q, off, 64);
    }
    if (o == 0) { f1[row] = p; f2[row] = q; }
}

// ---------------- k1b: f1max[b] = max_i f1[b,i] ----------------
__global__ __launch_bounds__(256) void k1b_max(
        const float* __restrict__ f1, float* __restrict__ f1max) {
    int b = blockIdx.x, t = threadIdx.x;
    float m = -3.4e38f;
    for (int i = t; i < Nn; i += 256) m = fmaxf(m, f1[b * Nn + i]);
#pragma unroll
    for (int off = 32; off > 0; off >>= 1) m = fmaxf(m, __shfl_down(m, off, 64));
    __shared__ float sm[4];
    if ((t & 63) == 0) sm[t >> 6] = m;
    __syncthreads();
    if (t == 0) f1max[b] = fmaxf(fmaxf(sm[0], sm[1]), fmaxf(sm[2], sm[3]));
}

// ------- k2a: stream adj -> dense bf16 P[i][j] = exp(val - Mf_j), column sums Dsum -------
// grid (Bn, Nn/256 colchunks, Nn/128 rowchunks), block 512. Branch-free streaming.
__global__ __launch_bounds__(512) void k2a_dense(
        const float* __restrict__ adj, const float* __restrict__ f1,
        const float* __restrict__ f2, const float* __restrict__ f1max_p,
        float* __restrict__ Dsum, unsigned short* __restrict__ P) {
    int b = blockIdx.x;
    int j0 = blockIdx.y * 256;
    int i0 = blockIdx.z * 128;
    int w = threadIdx.x >> 6, lane = threadIdx.x & 63;
    float f1max = f1max_p[b];
    float4 f2v = *(const float4*)&f2[b * Nn + j0 + 4 * lane];
    float Mf0 = fmaxf(lrelu(f1max + f2v.x), 0.f);
    float Mf1 = fmaxf(lrelu(f1max + f2v.y), 0.f);
    float Mf2 = fmaxf(lrelu(f1max + f2v.z), 0.f);
    float Mf3 = fmaxf(lrelu(f1max + f2v.w), 0.f);
    float s0 = 0.f, s1 = 0.f, s2 = 0.f, s3 = 0.f;
    const float* abase = adj + ((size_t)b * Nn) * Nn + j0 + 4 * lane;
    unsigned short* pbase = P + ((size_t)b * Nn) * Nn + j0 + 4 * lane;
    const float* f1b = f1 + b * Nn;

    for (int g = 0; g < 4; ++g) {
        int r0 = i0 + w + 32 * g;
        float4 av0 = *(const float4*)(abase + (size_t)(r0 +  0) * Nn);
        float4 av1 = *(const float4*)(abase + (size_t)(r0 +  8) * Nn);
        float4 av2 = *(const float4*)(abase + (size_t)(r0 + 16) * Nn);
        float4 av3 = *(const float4*)(abase + (size_t)(r0 + 24) * Nn);
        float fi0 = f1b[r0], fi1 = f1b[r0 + 8], fi2 = f1b[r0 + 16], fi3 = f1b[r0 + 24];
#define PROC(AV, FI, IROW)                                                     \
        {                                                                      \
            float e0 = __expf((AV.x != 0.f ? lrelu((FI) + f2v.x) : 0.f) - Mf0);\
            float e1 = __expf((AV.y != 0.f ? lrelu((FI) + f2v.y) : 0.f) - Mf1);\
            float e2 = __expf((AV.z != 0.f ? lrelu((FI) + f2v.z) : 0.f) - Mf2);\
            float e3 = __expf((AV.w != 0.f ? lrelu((FI) + f2v.w) : 0.f) - Mf3);\
            s0 += e0; s1 += e1; s2 += e2; s3 += e3;                            \
            uint2 pk;                                                          \
            pk.x = (unsigned)bfr(e0) | ((unsigned)bfr(e1) << 16);              \
            pk.y = (unsigned)bfr(e2) | ((unsigned)bfr(e3) << 16);              \
            *(uint2*)(pbase + (size_t)(IROW) * Nn) = pk;                       \
        }
        PROC(av0, fi0, r0 +  0)
        PROC(av1, fi1, r0 +  8)
        PROC(av2, fi2, r0 + 16)
        PROC(av3, fi3, r0 + 24)
#undef PROC
    }
    __shared__ float sred[8][256];
    sred[w][4 * lane + 0] = s0;
    sred[w][4 * lane + 1] = s1;
    sred[w][4 * lane + 2] = s2;
    sred[w][4 * lane + 3] = s3;
    __syncthreads();
    if (threadIdx.x < 256) {
        int c = threadIdx.x;
        float v = 0.f;
#pragma unroll
        for (int k = 0; k < 8; ++k) v += sred[k][c];
        atomicAdd(&Dsum[b * Nn + j0 + c], v);
    }
}

// ------- k2b: h~T[b][o][j] = bf16( h[b][j][o] / Dsum[b][j] )  (scale + transpose) -------
// grid (Bn, Nn/64), block 256
__global__ __launch_bounds__(256) void k2b_scale_T(
        const float* __restrict__ h, const float* __restrict__ Dsum,
        unsigned short* __restrict__ hTs) {
    int b = blockIdx.x;
    int j0 = blockIdx.y * 64;
    int t = threadIdx.x;
    __shared__ float Lh[64][68];   // 68-f32 row stride: 16B-aligned rows
    __shared__ float Rsh[64];
    if (t < 64) Rsh[t] = 1.f / Dsum[b * Nn + j0 + t];
#pragma unroll
    for (int q = 0; q < 4; ++q) {
        int fi = t + 256 * q;           // 0..1023 float4 slots
        int jj = fi >> 4, oq = fi & 15;
        float4 v = *(const float4*)(h + ((size_t)(b * Nn + j0 + jj)) * Fn + oq * 4);
        *(float4*)&Lh[jj][oq * 4] = v;
    }
    __syncthreads();
    int o = t >> 2, jg = (t & 3) * 16;
    unsigned wbuf[8];
#pragma unroll
    for (int s2 = 0; s2 < 8; ++s2) {
        int j = jg + 2 * s2;
        unsigned lo16 = bfr(Lh[j][o] * Rsh[j]);
        unsigned hi16 = bfr(Lh[j + 1][o] * Rsh[j + 1]);
        wbuf[s2] = lo16 | (hi16 << 16);
    }
    unsigned short* dst = hTs + ((size_t)(b * Fn + o)) * Nn + j0 + jg;
    *(uint4*)dst       = make_uint4(wbuf[0], wbuf[1], wbuf[2], wbuf[3]);
    *(uint4*)(dst + 8) = make_uint4(wbuf[4], wbuf[5], wbuf[6], wbuf[7]);
}

// ------- k3: GEMM  out[b][i][o] = elu( sum_j P[i][j]*h~T[o][j] + bias[i][o] + inp[b][i][o] )
// MFMA 16x16x32 bf16: D[m=o][n=i]. A = h~T (m=o,k=j), B = P (k=j,n=i); both frags contiguous 16B.
// grid (Bn, Nn/32), block 256: wave w -> i-tile (w>>1), o-half (w&1)*32.
__global__ __launch_bounds__(256) void k3_gemm(
        const unsigned short* __restrict__ P, const unsigned short* __restrict__ hTs,
        const float* __restrict__ inp, const float* __restrict__ bias,
        float* __restrict__ out) {
    int b = blockIdx.x;
    int w = threadIdx.x >> 6, lane = threadIdx.x & 63;
    int laneM = lane & 15, laneK = (lane >> 4) * 8;
    int i0 = blockIdx.y * 32 + (w >> 1) * 16;
    int o0 = (w & 1) * 32;
    const unsigned short* A0 = hTs + ((size_t)(b * Fn + o0 + laneM)) * Nn + laneK;
    const unsigned short* A1 = A0 + 16 * Nn;
    const unsigned short* Bp = P + ((size_t)(b * Nn + i0 + laneM)) * Nn + laneK;

    f4frag c0 = {0.f, 0.f, 0.f, 0.f}, c1 = {0.f, 0.f, 0.f, 0.f};
    s8frag a0 = *(const s8frag*)A0;
    s8frag a1 = *(const s8frag*)A1;
    s8frag bb = *(const s8frag*)Bp;
#pragma unroll 4
    for (int k0 = 32; k0 < Nn; k0 += 32) {
        s8frag na0 = *(const s8frag*)(A0 + k0);
        s8frag na1 = *(const s8frag*)(A1 + k0);
        s8frag nbb = *(const s8frag*)(Bp + k0);
        c0 = __builtin_amdgcn_mfma_f32_16x16x32_bf16(a0, bb, c0, 0, 0, 0);
        c1 = __builtin_amdgcn_mfma_f32_16x16x32_bf16(a1, bb, c1, 0, 0, 0);
        a0 = na0; a1 = na1; bb = nbb;
    }
    c0 = __builtin_amdgcn_mfma_f32_16x16x32_bf16(a0, bb, c0, 0, 0, 0);
    c1 = __builtin_amdgcn_mfma_f32_16x16x32_bf16(a1, bb, c1, 0, 0, 0);

    // epilogue: lane holds (i = i0+laneM, o = o0 + quad*4 + r) for c0, +16 for c1
    int i = i0 + laneM;
    int oA = o0 + (lane >> 4) * 4;
    size_t gbase = ((size_t)b * Nn + i) * Fn;
    float4 in0 = *(const float4*)(inp + gbase + oA);
    float4 in1 = *(const float4*)(inp + gbase + oA + 16);
    float4 bi0 = *(const float4*)(bias + (size_t)i * Fn + oA);
    float4 bi1 = *(const float4*)(bias + (size_t)i * Fn + oA + 16);
    float4 r0v, r1v;
    r0v.x = elu(c0[0] + in0.x + bi0.x);
    r0v.y = elu(c0[1] + in0.y + bi0.y);
    r0v.z = elu(c0[2] + in0.z + bi0.z);
    r0v.w = elu(c0[3] + in0.w + bi0.w);
    r1v.x = elu(c1[0] + in1.x + bi1.x);
    r1v.y = elu(c1[1] + in1.y + bi1.y);
    r1v.z = elu(c1[2] + in1.z + bi1.z);
    r1v.w = elu(c1[3] + in1.w + bi1.w);
    *(float4*)(out + gbase + oA) = r0v;
    *(float4*)(out + gbase + oA + 16) = r1v;
}

extern "C" void kernel_launch(void* const* d_in, const int* in_sizes, int n_in,
                              void* d_out, int out_size, void* d_ws, size_t ws_size,
                              hipStream_t stream) {
    const float* inp  = (const float*)d_in[0];
    const float* adj  = (const float*)d_in[1];
    const float* W    = (const float*)d_in[2];
    const float* a1   = (const float*)d_in[3];
    const float* a2   = (const float*)d_in[4];
    const float* bias = (const float*)d_in[5];
    float* out = (float*)d_out;

    // workspace layout (~74 MB; ws is 512 MiB)
    unsigned short* P   = (unsigned short*)d_ws;            // Bn*Nn*Nn bf16 = 64 MiB
    unsigned short* hTs = P + (size_t)Bn * Nn * Nn;         // Bn*Fn*Nn bf16 = 2 MiB
    float* h     = (float*)(hTs + (size_t)Bn * Fn * Nn);    // 4 MiB
    float* f1    = h + (size_t)Bn * Nn * Fn;                // 64 KiB
    float* f2    = f1 + (size_t)Bn * Nn;                    // 64 KiB
    float* Dsum  = f2 + (size_t)Bn * Nn;                    // 64 KiB (zeroed)
    float* f1max = Dsum + (size_t)Bn * Nn;                  // 32 B

    hipMemsetAsync(Dsum, 0, (size_t)Bn * Nn * sizeof(float), stream);
    k1_h_f<<<Bn * Nn / 4, 256, 0, stream>>>(inp, W, a1, a2, h, f1, f2);
    k1b_max<<<Bn, 256, 0, stream>>>(f1, f1max);
    k2a_dense<<<dim3(Bn, Nn / 256, Nn / 128), 512, 0, stream>>>(adj, f1, f2, f1max, Dsum, P);
    k2b_scale_T<<<dim3(Bn, Nn / 64), 256, 0, stream>>>(h, Dsum, hTs);
    k3_gemm<<<dim3(Bn, Nn / 32), 256, 0, stream>>>(P, hTs, inp, bias, out);
}

// Round 6
// 260.853 us; speedup vs baseline: 2.0009x; 1.0623x over previous
//
#include <hip/hip_runtime.h>
#include <cstdint>
#include <cstddef>

#define Bn 8
#define Nn 2048
#define Fn 64
#define ALPHA 0.2f

typedef __attribute__((ext_vector_type(8))) short  s8frag;   // 8 x bf16
typedef __attribute__((ext_vector_type(4))) float  f4frag;   // 4 x f32 acc

__device__ __forceinline__ float lrelu(float x) { return fmaxf(x, ALPHA * x); }
__device__ __forceinline__ float elu(float x)   { return x > 0.f ? x : __expf(x) - 1.f; }
// f32 -> bf16 round-to-nearest-even (values positive finite here)
__device__ __forceinline__ unsigned short bfr(float f) {
    unsigned u = __float_as_uint(f);
    u += 0x7fffu + ((u >> 16) & 1u);
    return (unsigned short)(u >> 16);
}

// ---------------- k1: h = input@W, f1 = h@a1, f2 = h@a2 ----------------
__global__ __launch_bounds__(256) void k1_h_f(
        const float* __restrict__ inp, const float* __restrict__ W,
        const float* __restrict__ a1, const float* __restrict__ a2,
        float* __restrict__ h, float* __restrict__ f1, float* __restrict__ f2) {
    __shared__ float Wl[Fn * Fn];
    __shared__ float inr[4 * Fn];
    int t = threadIdx.x;
    for (int k = t; k < Fn * Fn; k += 256) Wl[k] = W[k];
    size_t row0 = (size_t)blockIdx.x * 4;
    inr[t] = inp[row0 * Fn + t];
    __syncthreads();
    int r = t >> 6, o = t & 63;
    const float* irow = &inr[r * Fn];
    float acc = 0.f;
#pragma unroll
    for (int f = 0; f < Fn; ++f) acc = fmaf(irow[f], Wl[f * Fn + o], acc);
    size_t row = row0 + r;
    h[row * Fn + o] = acc;
    float p = acc * a1[o];
    float q = acc * a2[o];
#pragma unroll
    for (int off = 32; off > 0; off >>= 1) {
        p += __shfl_down(p, off, 64);
        q += __shfl_down(q, off, 64);
    }
    if (o == 0) { f1[row] = p; f2[row] = q; }
}

// ---------------- k1b: f1max[b] = max_i f1[b,i] ----------------
__global__ __launch_bounds__(256) void k1b_max(
        const float* __restrict__ f1, float* __restrict__ f1max) {
    int b = blockIdx.x, t = threadIdx.x;
    float m = -3.4e38f;
    for (int i = t; i < Nn; i += 256) m = fmaxf(m, f1[b * Nn + i]);
#pragma unroll
    for (int off = 32; off > 0; off >>= 1) m = fmaxf(m, __shfl_down(m, off, 64));
    __shared__ float sm[4];
    if ((t & 63) == 0) sm[t >> 6] = m;
    __syncthreads();
    if (t == 0) f1max[b] = fmaxf(fmaxf(sm[0], sm[1]), fmaxf(sm[2], sm[3]));
}

// ------- k2a: stream adj once -> bit-packed mask + column sums Dsum -------
// grid (Bn, 8 colchunks of 256, 16 rowchunks of 128), block 512.
// Bit layout (permuted for k3's per-lane contiguity):
//   bitsL[((b*8 + jc)*Nn + i)*32 + (j8&3)*8 + (j8>>2)], bit k of byte j8 = col jc*256 + 8*j8 + k
__global__ __launch_bounds__(512) void k2a_bits(
        const float* __restrict__ adj, const float* __restrict__ f1,
        const float* __restrict__ f2, const float* __restrict__ f1max_p,
        float* __restrict__ Dsum, unsigned char* __restrict__ bitsL) {
    int b = blockIdx.x;
    int cj = blockIdx.y;
    int j0 = cj * 256;
    int i0 = blockIdx.z * 128;
    int w = threadIdx.x >> 6, lane = threadIdx.x & 63;
    float f1max = f1max_p[b];
    float4 f2v = *(const float4*)&f2[b * Nn + j0 + 4 * lane];
    float Mf0 = fmaxf(lrelu(f1max + f2v.x), 0.f);
    float Mf1 = fmaxf(lrelu(f1max + f2v.y), 0.f);
    float Mf2 = fmaxf(lrelu(f1max + f2v.z), 0.f);
    float Mf3 = fmaxf(lrelu(f1max + f2v.w), 0.f);
    float s0 = 0.f, s1 = 0.f, s2 = 0.f, s3 = 0.f;
    const float* abase = adj + ((size_t)b * Nn) * Nn + j0 + 4 * lane;
    const float* f1b = f1 + b * Nn;
    int g = lane >> 1;                         // byte index 0..31 (j8)
    int boff = (g & 3) * 8 + (g >> 2);         // permuted byte slot
    bool evenlane = (lane & 1) == 0;
    size_t bbase = ((size_t)(b * 8 + cj) * Nn) * 32;

    for (int gi = 0; gi < 4; ++gi) {
        int r0 = i0 + w + 32 * gi;
        float4 av0 = *(const float4*)(abase + (size_t)(r0 +  0) * Nn);
        float4 av1 = *(const float4*)(abase + (size_t)(r0 +  8) * Nn);
        float4 av2 = *(const float4*)(abase + (size_t)(r0 + 16) * Nn);
        float4 av3 = *(const float4*)(abase + (size_t)(r0 + 24) * Nn);
        float fi0 = f1b[r0], fi1 = f1b[r0 + 8], fi2 = f1b[r0 + 16], fi3 = f1b[r0 + 24];
#define PROC(AV, FI, IROW)                                                     \
        {                                                                      \
            bool n0 = AV.x != 0.f, n1 = AV.y != 0.f,                           \
                 n2 = AV.z != 0.f, n3 = AV.w != 0.f;                           \
            s0 += __expf((n0 ? lrelu((FI) + f2v.x) : 0.f) - Mf0);              \
            s1 += __expf((n1 ? lrelu((FI) + f2v.y) : 0.f) - Mf1);              \
            s2 += __expf((n2 ? lrelu((FI) + f2v.z) : 0.f) - Mf2);              \
            s3 += __expf((n3 ? lrelu((FI) + f2v.w) : 0.f) - Mf3);              \
            unsigned nib = (unsigned)n0 | ((unsigned)n1 << 1) |                \
                           ((unsigned)n2 << 2) | ((unsigned)n3 << 3);          \
            unsigned other = __shfl_xor(nib, 1, 64);                           \
            if (evenlane)                                                      \
                bitsL[bbase + (size_t)(IROW) * 32 + boff] =                    \
                    (unsigned char)(nib | (other << 4));                       \
        }
        PROC(av0, fi0, r0 +  0)
        PROC(av1, fi1, r0 +  8)
        PROC(av2, fi2, r0 + 16)
        PROC(av3, fi3, r0 + 24)
#undef PROC
    }
    __shared__ float sred[8][256];
    sred[w][4 * lane + 0] = s0;
    sred[w][4 * lane + 1] = s1;
    sred[w][4 * lane + 2] = s2;
    sred[w][4 * lane + 3] = s3;
    __syncthreads();
    if (threadIdx.x < 256) {
        int c = threadIdx.x;
        float v = 0.f;
#pragma unroll
        for (int k = 0; k < 8; ++k) v += sred[k][c];
        atomicAdd(&Dsum[b * Nn + j0 + c], v);
    }
}

// ------- k2b: h~T[b][o][j] = bf16( h[b][j][o] / D_j )  +  cf[b][j] = {f2_j, Mf_j} -------
// grid (Bn, Nn/64), block 256
__global__ __launch_bounds__(256) void k2b_scale_T(
        const float* __restrict__ h, const float* __restrict__ Dsum,
        const float* __restrict__ f2, const float* __restrict__ f1max_p,
        unsigned short* __restrict__ hTs, float2* __restrict__ cf) {
    int b = blockIdx.x;
    int j0 = blockIdx.y * 64;
    int t = threadIdx.x;
    __shared__ float Lh[64][68];
    __shared__ float Rsh[64];
    if (t < 64) {
        int j = j0 + t;
        float f2j = f2[b * Nn + j];
        float Mf = fmaxf(lrelu(f1max_p[b] + f2j), 0.f);
        Rsh[t] = 1.f / Dsum[b * Nn + j];
        cf[b * Nn + j] = make_float2(f2j, Mf);
    }
#pragma unroll
    for (int q = 0; q < 4; ++q) {
        int fi = t + 256 * q;
        int jj = fi >> 4, oq = fi & 15;
        float4 v = *(const float4*)(h + ((size_t)(b * Nn + j0 + jj)) * Fn + oq * 4);
        *(float4*)&Lh[jj][oq * 4] = v;
    }
    __syncthreads();
    int o = t >> 2, jg = (t & 3) * 16;
    unsigned wbuf[8];
#pragma unroll
    for (int s2 = 0; s2 < 8; ++s2) {
        int j = jg + 2 * s2;
        unsigned lo16 = bfr(Lh[j][o] * Rsh[j]);
        unsigned hi16 = bfr(Lh[j + 1][o] * Rsh[j + 1]);
        wbuf[s2] = lo16 | (hi16 << 16);
    }
    unsigned short* dst = hTs + ((size_t)(b * Fn + o)) * Nn + j0 + jg;
    *(uint4*)dst       = make_uint4(wbuf[0], wbuf[1], wbuf[2], wbuf[3]);
    *(uint4*)(dst + 8) = make_uint4(wbuf[4], wbuf[5], wbuf[6], wbuf[7]);
}

// ------- k3: fused P-regeneration + MFMA GEMM + epilogue -------
// out[b][i][o] = elu( sum_j exp((bit? lrelu(f1_i+f2_j):0) - Mf_j) * h~T[o][j] + bias + inp )
// grid (Bn, Nn/64), block 256: wave w -> i rows [i0+16w, +16); 4 o-tiles per wave.
__global__ __launch_bounds__(256) void k3_fused(
        const unsigned char* __restrict__ bitsL,
        const unsigned short* __restrict__ hTs,
        const float2* __restrict__ cf, const float* __restrict__ f1,
        const float* __restrict__ inp, const float* __restrict__ bias,
        float* __restrict__ out) {
    int b = blockIdx.x;
    int i0 = blockIdx.y * 64;
    int w = threadIdx.x >> 6, lane = threadIdx.x & 63;
    int m = lane & 15, kg = lane >> 4;
    int i = i0 + w * 16 + m;

    __shared__ float2 cfL[Nn];
    {
        const float4* src = (const float4*)(cf + (size_t)b * Nn);
        float4* dst = (float4*)cfL;
        for (int q = threadIdx.x; q < Nn / 2; q += 256) dst[q] = src[q];
    }
    // preload this lane's mask bytes for the whole K sweep (8 B per 256-j chunk)
    uint2 pre[8];
#pragma unroll
    for (int jc = 0; jc < 8; ++jc)
        pre[jc] = *(const uint2*)(bitsL + ((size_t)(b * 8 + jc) * Nn + i) * 32 + kg * 8);
    float f1i = f1[b * Nn + i];
    __syncthreads();

    f4frag acc0 = {0.f,0.f,0.f,0.f}, acc1 = {0.f,0.f,0.f,0.f};
    f4frag acc2 = {0.f,0.f,0.f,0.f}, acc3 = {0.f,0.f,0.f,0.f};
    const unsigned short* Ab = hTs + (size_t)b * Fn * Nn + (size_t)m * Nn;

    for (int jc = 0; jc < 8; ++jc) {
        unsigned blo = pre[jc].x, bhi = pre[jc].y;
#pragma unroll 2
        for (int t = 0; t < 8; ++t) {
            unsigned bv = ((t < 4 ? blo : bhi) >> ((t & 3) * 8)) & 0xffu;
            int j = jc * 256 + t * 32 + kg * 8;
            const float2* cp = &cfL[j];
            s8frag bf;
#pragma unroll
            for (int r = 0; r < 8; ++r) {
                float2 c = cp[r];
                float l = lrelu(f1i + c.x);
                float arg = (((bv >> r) & 1u) ? l : 0.f) - c.y;
                bf[r] = (short)bfr(__expf(arg));
            }
            const unsigned short* Aj = Ab + j;
            s8frag a0 = *(const s8frag*)(Aj);
            s8frag a1 = *(const s8frag*)(Aj + 16 * Nn);
            s8frag a2 = *(const s8frag*)(Aj + 32 * Nn);
            s8frag a3 = *(const s8frag*)(Aj + 48 * Nn);
            acc0 = __builtin_amdgcn_mfma_f32_16x16x32_bf16(a0, bf, acc0, 0, 0, 0);
            acc1 = __builtin_amdgcn_mfma_f32_16x16x32_bf16(a1, bf, acc1, 0, 0, 0);
            acc2 = __builtin_amdgcn_mfma_f32_16x16x32_bf16(a2, bf, acc2, 0, 0, 0);
            acc3 = __builtin_amdgcn_mfma_f32_16x16x32_bf16(a3, bf, acc3, 0, 0, 0);
        }
    }
    // epilogue: lane holds D[o = ot*16 + kg*4 + r][i]
    size_t gbase = ((size_t)b * Nn + i) * Fn;
    int ob = kg * 4;
    f4frag accs[4] = {acc0, acc1, acc2, acc3};
#pragma unroll
    for (int ot = 0; ot < 4; ++ot) {
        int o = ot * 16 + ob;
        float4 iv  = *(const float4*)(inp + gbase + o);
        float4 bv4 = *(const float4*)(bias + (size_t)i * Fn + o);
        float4 r;
        r.x = elu(accs[ot][0] + iv.x + bv4.x);
        r.y = elu(accs[ot][1] + iv.y + bv4.y);
        r.z = elu(accs[ot][2] + iv.z + bv4.z);
        r.w = elu(accs[ot][3] + iv.w + bv4.w);
        *(float4*)(out + gbase + o) = r;
    }
}

extern "C" void kernel_launch(void* const* d_in, const int* in_sizes, int n_in,
                              void* d_out, int out_size, void* d_ws, size_t ws_size,
                              hipStream_t stream) {
    const float* inp  = (const float*)d_in[0];
    const float* adj  = (const float*)d_in[1];
    const float* W    = (const float*)d_in[2];
    const float* a1   = (const float*)d_in[3];
    const float* a2   = (const float*)d_in[4];
    const float* bias = (const float*)d_in[5];
    float* out = (float*)d_out;

    // workspace layout (~10.5 MiB)
    unsigned char* bitsL = (unsigned char*)d_ws;               // Bn*Nn*Nn/8 = 4 MiB
    unsigned short* hTs  = (unsigned short*)(bitsL + (size_t)Bn * Nn * Nn / 8); // 2 MiB
    float* h     = (float*)(hTs + (size_t)Bn * Fn * Nn);       // 4 MiB
    float* f1    = h + (size_t)Bn * Nn * Fn;                   // 64 KiB
    float* f2    = f1 + (size_t)Bn * Nn;                       // 64 KiB
    float* Dsum  = f2 + (size_t)Bn * Nn;                       // 64 KiB (zeroed)
    float2* cf   = (float2*)(Dsum + (size_t)Bn * Nn);          // 128 KiB
    float* f1max = (float*)(cf + (size_t)Bn * Nn);             // 32 B

    hipMemsetAsync(Dsum, 0, (size_t)Bn * Nn * sizeof(float), stream);
    k1_h_f<<<Bn * Nn / 4, 256, 0, stream>>>(inp, W, a1, a2, h, f1, f2);
    k1b_max<<<Bn, 256, 0, stream>>>(f1, f1max);
    k2a_bits<<<dim3(Bn, 8, 16), 512, 0, stream>>>(adj, f1, f2, f1max, Dsum, bitsL);
    k2b_scale_T<<<dim3(Bn, Nn / 64), 256, 0, stream>>>(h, Dsum, f2, f1max, hTs, cf);
    k3_fused<<<dim3(Bn, Nn / 64), 256, 0, stream>>>(bitsL, hTs, cf, f1, inp, bias, out);
}

// Round 7
// 258.663 us; speedup vs baseline: 2.0179x; 1.0085x over previous
//
#include <hip/hip_runtime.h>
#include <cstdint>
#include <cstddef>

#define Bn 8
#define Nn 2048
#define Fn 64
#define ALPHA 0.2f

typedef __attribute__((ext_vector_type(8))) short  s8frag;   // 8 x bf16
typedef __attribute__((ext_vector_type(4))) float  f4frag;   // 4 x f32 acc

__device__ __forceinline__ float lrelu(float x) { return fmaxf(x, ALPHA * x); }
__device__ __forceinline__ float elu(float x)   { return x > 0.f ? x : __expf(x) - 1.f; }
// f32 -> bf16 round-to-nearest-even (values positive finite here)
__device__ __forceinline__ unsigned short bfr(float f) {
    unsigned u = __float_as_uint(f);
    u += 0x7fffu + ((u >> 16) & 1u);
    return (unsigned short)(u >> 16);
}

// ---------------- k1: h = input@W, f1 = h@a1, f2 = h@a2 ----------------
__global__ __launch_bounds__(256) void k1_h_f(
        const float* __restrict__ inp, const float* __restrict__ W,
        const float* __restrict__ a1, const float* __restrict__ a2,
        float* __restrict__ h, float* __restrict__ f1, float* __restrict__ f2) {
    __shared__ float Wl[Fn * Fn];
    __shared__ float inr[4 * Fn];
    int t = threadIdx.x;
    for (int k = t; k < Fn * Fn; k += 256) Wl[k] = W[k];
    size_t row0 = (size_t)blockIdx.x * 4;
    inr[t] = inp[row0 * Fn + t];
    __syncthreads();
    int r = t >> 6, o = t & 63;
    const float* irow = &inr[r * Fn];
    float acc = 0.f;
#pragma unroll
    for (int f = 0; f < Fn; ++f) acc = fmaf(irow[f], Wl[f * Fn + o], acc);
    size_t row = row0 + r;
    h[row * Fn + o] = acc;
    float p = acc * a1[o];
    float q = acc * a2[o];
#pragma unroll
    for (int off = 32; off > 0; off >>= 1) {
        p += __shfl_down(p, off, 64);
        q += __shfl_down(q, off, 64);
    }
    if (o == 0) { f1[row] = p; f2[row] = q; }
}

// ---------------- k1b: f1max[b] = max_i f1[b,i] ----------------
__global__ __launch_bounds__(256) void k1b_max(
        const float* __restrict__ f1, float* __restrict__ f1max) {
    int b = blockIdx.x, t = threadIdx.x;
    float m = -3.4e38f;
    for (int i = t; i < Nn; i += 256) m = fmaxf(m, f1[b * Nn + i]);
#pragma unroll
    for (int off = 32; off > 0; off >>= 1) m = fmaxf(m, __shfl_down(m, off, 64));
    __shared__ float sm[4];
    if ((t & 63) == 0) sm[t >> 6] = m;
    __syncthreads();
    if (t == 0) f1max[b] = fmaxf(fmaxf(sm[0], sm[1]), fmaxf(sm[2], sm[3]));
}

// ------- k2a: stream adj once -> bit-packed mask + column sums Dsum (rank-1, exp-free) -------
// grid (Bn, 8 colchunks of 256, 16 rowchunks of 128), block 512.
// Bit layout: bitsL[((b*8+jc)*Nn + i)*32 + (j8&3)*8 + (j8>>2)], bit k of byte j8 = col jc*256+8*j8+k
__global__ __launch_bounds__(512) void k2a_bits(
        const float* __restrict__ adj, const float* __restrict__ f1,
        const float* __restrict__ f2, const float* __restrict__ f1max_p,
        float* __restrict__ Dsum, unsigned char* __restrict__ bitsL) {
    int b = blockIdx.x;
    int cj = blockIdx.y;
    int j0 = cj * 256;
    int i0 = blockIdx.z * 128;
    int w = threadIdx.x >> 6, lane = threadIdx.x & 63;
    float f1max = f1max_p[b];
    float4 f2v = *(const float4*)&f2[b * Nn + j0 + 4 * lane];
    float Mf0 = fmaxf(lrelu(f1max + f2v.x), 0.f);
    float Mf1 = fmaxf(lrelu(f1max + f2v.y), 0.f);
    float Mf2 = fmaxf(lrelu(f1max + f2v.z), 0.f);
    float Mf3 = fmaxf(lrelu(f1max + f2v.w), 0.f);
    float vh0 = __expf(f2v.x - Mf0), vp0 = __expf(ALPHA * f2v.x - Mf0), ez0 = __expf(-Mf0);
    float vh1 = __expf(f2v.y - Mf1), vp1 = __expf(ALPHA * f2v.y - Mf1), ez1 = __expf(-Mf1);
    float vh2 = __expf(f2v.z - Mf2), vp2 = __expf(ALPHA * f2v.z - Mf2), ez2 = __expf(-Mf2);
    float vh3 = __expf(f2v.w - Mf3), vp3 = __expf(ALPHA * f2v.w - Mf3), ez3 = __expf(-Mf3);
    float s0 = 0.f, s1 = 0.f, s2 = 0.f, s3 = 0.f;
    const float* abase = adj + ((size_t)b * Nn) * Nn + j0 + 4 * lane;
    const float* f1b = f1 + b * Nn;
    int g = lane >> 1;
    int boff = (g & 3) * 8 + (g >> 2);
    bool evenlane = (lane & 1) == 0;
    size_t bbase = ((size_t)(b * 8 + cj) * Nn) * 32;

    int rb = i0 + w;
    float4 av0 = *(const float4*)(abase + (size_t)(rb +  0) * Nn);
    float4 av1 = *(const float4*)(abase + (size_t)(rb +  8) * Nn);
    float4 av2 = *(const float4*)(abase + (size_t)(rb + 16) * Nn);
    float4 av3 = *(const float4*)(abase + (size_t)(rb + 24) * Nn);
    float fi0 = f1b[rb], fi1 = f1b[rb + 8], fi2 = f1b[rb + 16], fi3 = f1b[rb + 24];

    for (int gi = 0; gi < 4; ++gi) {
        int rc = i0 + w + 32 * gi;
        float4 nv0, nv1, nv2, nv3;
        float nf0 = 0.f, nf1 = 0.f, nf2 = 0.f, nf3 = 0.f;
        if (gi < 3) {
            int rn = rc + 32;
            nv0 = *(const float4*)(abase + (size_t)(rn +  0) * Nn);
            nv1 = *(const float4*)(abase + (size_t)(rn +  8) * Nn);
            nv2 = *(const float4*)(abase + (size_t)(rn + 16) * Nn);
            nv3 = *(const float4*)(abase + (size_t)(rn + 24) * Nn);
            nf0 = f1b[rn]; nf1 = f1b[rn + 8]; nf2 = f1b[rn + 16]; nf3 = f1b[rn + 24];
        }
#define PROC(AV, FI, IROW)                                                     \
        {                                                                      \
            float u  = __expf(FI);                                             \
            float up = __expf(ALPHA * (FI));                                   \
            bool n0 = AV.x != 0.f, n1 = AV.y != 0.f,                           \
                 n2 = AV.z != 0.f, n3 = AV.w != 0.f;                           \
            float x0 = (FI) + f2v.x, x1 = (FI) + f2v.y,                        \
                  x2 = (FI) + f2v.z, x3 = (FI) + f2v.w;                        \
            float e0 = x0 > 0.f ? u * vh0 : up * vp0;                          \
            float e1 = x1 > 0.f ? u * vh1 : up * vp1;                          \
            float e2 = x2 > 0.f ? u * vh2 : up * vp2;                          \
            float e3 = x3 > 0.f ? u * vh3 : up * vp3;                          \
            s0 += n0 ? e0 : ez0;                                               \
            s1 += n1 ? e1 : ez1;                                               \
            s2 += n2 ? e2 : ez2;                                               \
            s3 += n3 ? e3 : ez3;                                               \
            unsigned nib = (unsigned)n0 | ((unsigned)n1 << 1) |                \
                           ((unsigned)n2 << 2) | ((unsigned)n3 << 3);          \
            unsigned other = __shfl_xor(nib, 1, 64);                           \
            if (evenlane)                                                      \
                bitsL[bbase + (size_t)(IROW) * 32 + boff] =                    \
                    (unsigned char)(nib | (other << 4));                       \
        }
        PROC(av0, fi0, rc +  0)
        PROC(av1, fi1, rc +  8)
        PROC(av2, fi2, rc + 16)
        PROC(av3, fi3, rc + 24)
#undef PROC
        av0 = nv0; av1 = nv1; av2 = nv2; av3 = nv3;
        fi0 = nf0; fi1 = nf1; fi2 = nf2; fi3 = nf3;
    }
    __shared__ float sred[8][256];
    sred[w][4 * lane + 0] = s0;
    sred[w][4 * lane + 1] = s1;
    sred[w][4 * lane + 2] = s2;
    sred[w][4 * lane + 3] = s3;
    __syncthreads();
    if (threadIdx.x < 256) {
        int c = threadIdx.x;
        float v = 0.f;
#pragma unroll
        for (int k = 0; k < 8; ++k) v += sred[k][c];
        atomicAdd(&Dsum[b * Nn + j0 + c], v);
    }
}

// ------- k2b: h~T[b][o][j] = bf16( h[b][j][o] / D_j )  +  cf4[b][j] = {f2, v^, v^', ez} -------
// grid (Bn, Nn/64), block 256
__global__ __launch_bounds__(256) void k2b_scale_T(
        const float* __restrict__ h, const float* __restrict__ Dsum,
        const float* __restrict__ f2, const float* __restrict__ f1max_p,
        unsigned short* __restrict__ hTs, float4* __restrict__ cf4) {
    int b = blockIdx.x;
    int j0 = blockIdx.y * 64;
    int t = threadIdx.x;
    __shared__ float Lh[64][68];
    __shared__ float Rsh[64];
    if (t < 64) {
        int j = j0 + t;
        float f2j = f2[b * Nn + j];
        float Mf = fmaxf(lrelu(f1max_p[b] + f2j), 0.f);
        Rsh[t] = 1.f / Dsum[b * Nn + j];
        cf4[b * Nn + j] = make_float4(f2j, __expf(f2j - Mf),
                                      __expf(ALPHA * f2j - Mf), __expf(-Mf));
    }
#pragma unroll
    for (int q = 0; q < 4; ++q) {
        int fi = t + 256 * q;
        int jj = fi >> 4, oq = fi & 15;
        float4 v = *(const float4*)(h + ((size_t)(b * Nn + j0 + jj)) * Fn + oq * 4);
        *(float4*)&Lh[jj][oq * 4] = v;
    }
    __syncthreads();
    int o = t >> 2, jg = (t & 3) * 16;
    unsigned wbuf[8];
#pragma unroll
    for (int s2 = 0; s2 < 8; ++s2) {
        int j = jg + 2 * s2;
        unsigned lo16 = bfr(Lh[j][o] * Rsh[j]);
        unsigned hi16 = bfr(Lh[j + 1][o] * Rsh[j + 1]);
        wbuf[s2] = lo16 | (hi16 << 16);
    }
    unsigned short* dst = hTs + ((size_t)(b * Fn + o)) * Nn + j0 + jg;
    *(uint4*)dst       = make_uint4(wbuf[0], wbuf[1], wbuf[2], wbuf[3]);
    *(uint4*)(dst + 8) = make_uint4(wbuf[4], wbuf[5], wbuf[6], wbuf[7]);
}

// ------- k3: fused P-regen (exp-free) + MFMA GEMM, K-split across 4 waves -------
// grid (Bn, Nn/16), block 256: block = 16-row i-tile; wave w -> K quarter [w*512,(w+1)*512)
__global__ __launch_bounds__(256) void k3_fused(
        const unsigned char* __restrict__ bitsL,
        const unsigned short* __restrict__ hTs,
        const float4* __restrict__ cf4, const float* __restrict__ f1,
        const float* __restrict__ inp, const float* __restrict__ bias,
        float* __restrict__ out) {
    int b = blockIdx.x;
    int i0 = blockIdx.y * 16;
    int w = threadIdx.x >> 6, lane = threadIdx.x & 63;
    int m = lane & 15, kg = lane >> 4;
    int i = i0 + m;

    __shared__ float4 shb[Nn];   // 32 KB: column table, then reduction buffer
    {
        const float4* src = cf4 + (size_t)b * Nn;
        for (int q = threadIdx.x; q < Nn; q += 256) shb[q] = src[q];
    }
    uint2 pre0 = *(const uint2*)(bitsL + ((size_t)(b * 8 + 2 * w) * Nn + i) * 32 + kg * 8);
    uint2 pre1 = *(const uint2*)(bitsL + ((size_t)(b * 8 + 2 * w + 1) * Nn + i) * 32 + kg * 8);
    float f1i = f1[b * Nn + i];
    float ui = __expf(f1i), upi = __expf(ALPHA * f1i);
    __syncthreads();

    f4frag acc0 = {0.f,0.f,0.f,0.f}, acc1 = {0.f,0.f,0.f,0.f};
    f4frag acc2 = {0.f,0.f,0.f,0.f}, acc3 = {0.f,0.f,0.f,0.f};
    const unsigned short* Ab = hTs + (size_t)b * Fn * Nn + (size_t)m * Nn;

    for (int jcl = 0; jcl < 2; ++jcl) {
        int jc = 2 * w + jcl;
        unsigned blo = jcl ? pre1.x : pre0.x;
        unsigned bhi = jcl ? pre1.y : pre0.y;
#pragma unroll 2
        for (int t = 0; t < 8; ++t) {
            unsigned bv = ((t < 4 ? blo : bhi) >> ((t & 3) * 8)) & 0xffu;
            int j = jc * 256 + t * 32 + kg * 8;
            s8frag bf;
#pragma unroll
            for (int r = 0; r < 8; ++r) {
                float4 c = shb[j + r];
                float x = f1i + c.x;
                float uv = x > 0.f ? ui * c.y : upi * c.z;
                float val = ((bv >> r) & 1u) ? uv : c.w;
                bf[r] = (short)bfr(val);
            }
            const unsigned short* Aj = Ab + j;
            s8frag a0 = *(const s8frag*)(Aj);
            s8frag a1 = *(const s8frag*)(Aj + 16 * Nn);
            s8frag a2 = *(const s8frag*)(Aj + 32 * Nn);
            s8frag a3 = *(const s8frag*)(Aj + 48 * Nn);
            acc0 = __builtin_amdgcn_mfma_f32_16x16x32_bf16(a0, bf, acc0, 0, 0, 0);
            acc1 = __builtin_amdgcn_mfma_f32_16x16x32_bf16(a1, bf, acc1, 0, 0, 0);
            acc2 = __builtin_amdgcn_mfma_f32_16x16x32_bf16(a2, bf, acc2, 0, 0, 0);
            acc3 = __builtin_amdgcn_mfma_f32_16x16x32_bf16(a3, bf, acc3, 0, 0, 0);
        }
    }
    // cross-wave K reduction in LDS (reuse shb), then epilogue
    __syncthreads();
    f4frag accs[4] = {acc0, acc1, acc2, acc3};
#pragma unroll
    for (int ot = 0; ot < 4; ++ot)
        shb[(w * 64 + lane) * 4 + ot] =
            make_float4(accs[ot][0], accs[ot][1], accs[ot][2], accs[ot][3]);
    __syncthreads();
    int il = threadIdx.x & 15, oq = threadIdx.x >> 4;   // oq 0..15
    int ot = oq >> 2, kg2 = oq & 3;
    float4 v = make_float4(0.f, 0.f, 0.f, 0.f);
#pragma unroll
    for (int ww = 0; ww < 4; ++ww) {
        float4 p = shb[(ww * 64 + kg2 * 16 + il) * 4 + ot];
        v.x += p.x; v.y += p.y; v.z += p.z; v.w += p.w;
    }
    int o = oq * 4;
    size_t gbase = ((size_t)b * Nn + i0 + il) * Fn + o;
    float4 iv  = *(const float4*)(inp + gbase);
    float4 bv4 = *(const float4*)(bias + (size_t)(i0 + il) * Fn + o);
    float4 r;
    r.x = elu(v.x + iv.x + bv4.x);
    r.y = elu(v.y + iv.y + bv4.y);
    r.z = elu(v.z + iv.z + bv4.z);
    r.w = elu(v.w + iv.w + bv4.w);
    *(float4*)(out + gbase) = r;
}

extern "C" void kernel_launch(void* const* d_in, const int* in_sizes, int n_in,
                              void* d_out, int out_size, void* d_ws, size_t ws_size,
                              hipStream_t stream) {
    const float* inp  = (const float*)d_in[0];
    const float* adj  = (const float*)d_in[1];
    const float* W    = (const float*)d_in[2];
    const float* a1   = (const float*)d_in[3];
    const float* a2   = (const float*)d_in[4];
    const float* bias = (const float*)d_in[5];
    float* out = (float*)d_out;

    // workspace layout (~10.6 MiB)
    unsigned char* bitsL = (unsigned char*)d_ws;                               // 4 MiB
    unsigned short* hTs  = (unsigned short*)(bitsL + (size_t)Bn * Nn * Nn / 8); // 2 MiB
    float* h     = (float*)(hTs + (size_t)Bn * Fn * Nn);       // 4 MiB
    float* f1    = h + (size_t)Bn * Nn * Fn;                   // 64 KiB
    float* f2    = f1 + (size_t)Bn * Nn;                       // 64 KiB
    float* Dsum  = f2 + (size_t)Bn * Nn;                       // 64 KiB (zeroed)
    float4* cf4  = (float4*)(Dsum + (size_t)Bn * Nn);          // 256 KiB
    float* f1max = (float*)(cf4 + (size_t)Bn * Nn);            // 32 B

    hipMemsetAsync(Dsum, 0, (size_t)Bn * Nn * sizeof(float), stream);
    k1_h_f<<<Bn * Nn / 4, 256, 0, stream>>>(inp, W, a1, a2, h, f1, f2);
    k1b_max<<<Bn, 256, 0, stream>>>(f1, f1max);
    k2a_bits<<<dim3(Bn, 8, 16), 512, 0, stream>>>(adj, f1, f2, f1max, Dsum, bitsL);
    k2b_scale_T<<<dim3(Bn, Nn / 64), 256, 0, stream>>>(h, Dsum, f2, f1max, hTs, cf4);
    k3_fused<<<dim3(Bn, Nn / 16), 256, 0, stream>>>(bitsL, hTs, cf4, f1, inp, bias, out);
}